// Round 14
// baseline (75.656 us; speedup 1.0000x reference)
//
#include <hip/hip_runtime.h>
#include <stdint.h>

#define NS 9

typedef _Float16 f16x8 __attribute__((ext_vector_type(8)));
typedef float    f32x4 __attribute__((ext_vector_type(4)));

#define SBAR __builtin_amdgcn_sched_barrier(0)
#define WAIT_VM(N) do { SBAR; asm volatile("s_waitcnt vmcnt(" #N ")" ::: "memory"); SBAR; } while (0)
#define WAIT_LGKM(N) do { SBAR; asm volatile("s_waitcnt lgkmcnt(" #N ")" ::: "memory"); SBAR; } while (0)

__device__ __forceinline__ unsigned int pk(float a, float b) {
    return __builtin_bit_cast(unsigned int, __builtin_amdgcn_cvt_pkrtz(a, b));
}

// out[b,h,A,C,j] = sum_d q[b,h,A,C,d]*relw[63+j-C,d] + q[b,h,C,A,d]*relh[63+j-C,d]
// v14: one 16x16 tile per 256-thread block, 32 KiB LDS, up to 5 blocks/CU
// (20 waves) -- v13 confirmed the family is latency-bound and waves/CU is the
// lever (v11: all pipes <5%). Only the row-scattered orientation q[Ta+jl][Tc+cl]
// needs LDS (16 KiB lane stride); the relh-term A-frag q[Tc+cl][Ta+jl] has a
// WAVE-UNIFORM row -> direct per-lane global loads within one 4 KiB L2-resident
// row (v8-verified pattern), and B-frags load directly from the L1/L2-resident
// rel tables (v8-verified, row clamp 71). Fragment pipeline: 8 groups of 6
// float4, 2-deep, counted vmcnt(6). Coalesced q traffic stays read-once (16
// tiles partition AxC). All layout/swizzle formulas verbatim v13 (passed).

__global__ __launch_bounds__(256, 5) void relpos_kernel(
    const float* __restrict__ q,
    const float* __restrict__ relh,
    const float* __restrict__ relw,
    float* __restrict__ out)
{
    __shared__ uint4 S1[16][16][8];      // 32 KiB f16: q[Ta0+al][Tc0+cc]

    const int blk  = blockIdx.x;
    const int bh   = blk & 127;          // b*8+h; stride 128 -> same XCD
    const int tile = blk >> 7;           // 0..15
    const int Ta0  = (tile >> 2) << 4;
    const int Tc0  = (tile & 3) << 4;

    const int t    = threadIdx.x;
    const int lane = t & 63;
    const int wvu  = __builtin_amdgcn_readfirstlane(t >> 6);   // 0..3
    const int jl   = lane & 15;
    const int k4p  = lane >> 4;

    const float* __restrict__ qs = q + ((size_t)bh << 18);

    // ---- stage S1 (coalesced): 16 float4/thread in 2 groups of 8 ----
    float4 sA[16];
#pragma unroll
    for (int i = 0; i < 8; ++i) {        // F = i*256 + t, al 0..7
        const int F = (i << 8) + t;
        const int al = F >> 8, cc = (F >> 4) & 15, g = F & 15;
        sA[i] = *(const float4*)(qs + (size_t)(Ta0 + al) * 4096
                                    + (size_t)(Tc0 + cc) * 64 + (g << 2));
    }
    SBAR;
#pragma unroll
    for (int i = 8; i < 16; ++i) {       // al 8..15
        const int F = (i << 8) + t;
        const int al = F >> 8, cc = (F >> 4) & 15, g = F & 15;
        sA[i] = *(const float4*)(qs + (size_t)(Ta0 + al) * 4096
                                    + (size_t)(Tc0 + cc) * 64 + (g << 2));
    }
    SBAR;

    // ---- fragment group (it,kh): A2 (2) + Bw (2) + Bh (2) float4 ----
    auto issueFrag = [&](int it, int kh, float4* dst) {
        const int cl = (wvu << 2) | it;
        const float* a2 = qs + (size_t)(Tc0 + cl) * 4096 + (size_t)(Ta0 + jl) * 64
                             + kh * 32 + k4p * 8;
        int rl = 63 - (Tc0 + cl) + jl;  if (rl > 71) rl = 71;   // junk lanes only
        const float* bw = relw + (size_t)rl * 64 + kh * 32 + k4p * 8;
        const float* bp = relh + (size_t)rl * 64 + kh * 32 + k4p * 8;
        dst[0] = *(const float4*)a2; dst[1] = *(const float4*)(a2 + 4);
        dst[2] = *(const float4*)bw; dst[3] = *(const float4*)(bw + 4);
        dst[4] = *(const float4*)bp; dst[5] = *(const float4*)(bp + 4);
        SBAR;
    };
    auto mku = [&](const float4& a, const float4& b) -> uint4 {
        uint4 u;
        u.x = pk(a.x, a.y); u.y = pk(a.z, a.w);
        u.z = pk(b.x, b.y); u.w = pk(b.z, b.w);
        return u;
    };

    float4 f0[6], f1[6];
    issueFrag(0, 0, f0);                 // 22 outstanding

    WAIT_VM(14);                         // stage group 0 landed
#pragma unroll
    for (int i = 0; i < 8; ++i) {
        const int F = (i << 8) + t;
        const int al = F >> 8, cc = (F >> 4) & 15, g = F & 15;
        const int slot = (g >> 1) ^ ((al ^ cc) & 7), half = g & 1;
        uint2 w; w.x = pk(sA[i].x, sA[i].y); w.y = pk(sA[i].z, sA[i].w);
        ((uint2*)&S1[al][cc][slot])[half] = w;
    }
    WAIT_VM(6);                          // stage group 1 landed
#pragma unroll
    for (int i = 8; i < 16; ++i) {
        const int F = (i << 8) + t;
        const int al = F >> 8, cc = (F >> 4) & 15, g = F & 15;
        const int slot = (g >> 1) ^ ((al ^ cc) & 7), half = g & 1;
        uint2 w; w.x = pk(sA[i].x, sA[i].y); w.y = pk(sA[i].z, sA[i].w);
        ((uint2*)&S1[al][cc][slot])[half] = w;
    }
    issueFrag(0, 1, f1);                 // 2 frag groups in flight
    WAIT_LGKM(0);
    __builtin_amdgcn_s_barrier();        // publish S1

    // ---- compute: 8 groups (it 0..3 x kh 0..1), 2-deep pipeline ----
    f32x4 acc[4];
#pragma unroll
    for (int i = 0; i < 4; ++i) acc[i] = (f32x4){0.f, 0.f, 0.f, 0.f};

#pragma unroll
    for (int g = 0; g < 8; ++g) {
        const int it = g >> 1, kh = g & 1;
        const int cl = (wvu << 2) | it;
        float4* fb = (g & 1) ? f1 : f0;
        // A1 (LDS row-read): S1[jl][cl], slot (kh*4 + k4p) ^ ((jl^cl)&7)
        const uint4 A1 = S1[jl][cl][((kh << 2) + k4p) ^ ((jl ^ cl) & 7)];
        if (g < 6) { WAIT_VM(6); } else { WAIT_VM(0); }     // group g landed
        const uint4 A2u = mku(fb[0], fb[1]);
        const uint4 Bwu = mku(fb[2], fb[3]);
        const uint4 Bhu = mku(fb[4], fb[5]);
        if (g + 2 < 8) issueFrag((g + 2) >> 1, (g + 2) & 1, fb);
        WAIT_LGKM(0);                     // A1 ready
        acc[it] = __builtin_amdgcn_mfma_f32_16x16x32_f16(
            __builtin_bit_cast(f16x8, A1), __builtin_bit_cast(f16x8, Bwu),
            acc[it], 0, 0, 0);
        acc[it] = __builtin_amdgcn_mfma_f32_16x16x32_f16(
            __builtin_bit_cast(f16x8, A2u), __builtin_bit_cast(f16x8, Bhu),
            acc[it], 0, 0, 0);
    }

    // ---- store: col j=lane&15 (<9), row a=(lane>>4)*4+reg ----
    if (jl < NS) {
        const int ar = k4p << 2;
        const size_t ob = (size_t)bh << 6;
#pragma unroll
        for (int it = 0; it < 4; ++it) {
            const int cl = (wvu << 2) | it;
#pragma unroll
            for (int r = 0; r < 4; ++r)
                out[((ob + (Ta0 + ar + r)) * 64 + (Tc0 + cl)) * NS + jl] = acc[it][r];
        }
    }
}

extern "C" void kernel_launch(void* const* d_in, const int* in_sizes, int n_in,
                              void* d_out, int out_size, void* d_ws, size_t ws_size,
                              hipStream_t stream) {
    const float* q    = (const float*)d_in[0];
    const float* relh = (const float*)d_in[3];
    const float* relw = (const float*)d_in[4];
    float* out = (float*)d_out;

    // grid: 16 tiles x 128 bh; 256-thread blocks, 32 KiB LDS
    relpos_kernel<<<dim3(2048), dim3(256), 0, stream>>>(q, relh, relw, out);
}

// Round 15
// 34.345 us; speedup vs baseline: 2.2028x; 2.2028x over previous
//
#include <hip/hip_runtime.h>
#include <stdint.h>

#define NS 9

typedef _Float16 f16x8 __attribute__((ext_vector_type(8)));
typedef float    f32x4 __attribute__((ext_vector_type(4)));

#define SBAR __builtin_amdgcn_sched_barrier(0)
#define WAIT_VM(N) do { SBAR; asm volatile("s_waitcnt vmcnt(" #N ")" ::: "memory"); SBAR; } while (0)
#define WAIT_LGKM(N) do { SBAR; asm volatile("s_waitcnt lgkmcnt(" #N ")" ::: "memory"); SBAR; } while (0)

__device__ __forceinline__ unsigned int pk(float a, float b) {
    return __builtin_bit_cast(unsigned int, __builtin_amdgcn_cvt_pkrtz(a, b));
}

// out[b,h,A,C,j] = sum_d q[b,h,A,C,d]*relw[63+j-C,d] + q[b,h,C,A,d]*relh[63+j-C,d]
// v15 = v13 (31.2us: 512-thr pair-tile blocks) made PERSISTENT + STREAMING:
// grid 512; block b loops units (wid,bh) = (w0,bh),(w0+4,bh),(w0+8,bh), w0=b>>7
// (2-3 units, per-bh 4 blocks cover all 10 pairs; per-CU balance exact; same
// bh -> same XCD, L2-warm q slab). Loads for unit u+1 are issued right after
// unit u's LDS writes, BEFORE the publish barrier -> HBM never idles during
// compute (v13's stage->drain->compute cycle left HBM dark ~50% of the time).
// Iter start uses WAIT_VM(0): counted waits are unsound once stores can retire
// early (v11 bug, diagnosed r14); stores are ~a compute-phase old, so cheap.
// launch_bounds(512,2): allow ~170 VGPR (staging prefetch + frags overlap);
// 1 block/CU -- the streaming bet vs v13's 2-block TLP.
// All layout/swizzle/fragment formulas verbatim v13 (passed, absmax 0.03125).

__global__ __launch_bounds__(512, 2) void relpos_kernel(
    const float* __restrict__ q,
    const float* __restrict__ relh,
    const float* __restrict__ relw,
    float* __restrict__ out)
{
    __shared__ uint4 S1[16][16][8];      // 32 KiB f16: q[Ta0+al][Tc0+cc]
    __shared__ uint4 S2[16][16][8];      // 32 KiB f16: q[Tc0+al][Ta0+cc]
    __shared__ uint4 RL[2][2][32][8];    // 16 KiB f16: [win][tbl][row][slot]

    const int b   = blockIdx.x;          // 0..511
    const int bh  = b & 127;             // same bh for all of this block's units
    const int w0  = b >> 7;              // 0..3
    const int nu  = (w0 < 2) ? 3 : 2;    // units: w0, w0+4, (w0+8 if <10)

    const int t    = threadIdx.x;        // 0..511
    const int lane = t & 63;
    const int wvu  = __builtin_amdgcn_readfirstlane(t >> 6);   // 0..7
    const int wg   = wvu >> 2;           // 0: tile (ta,tc), 1: twin (tc,ta)
    const int wl   = wvu & 3;
    const int jl   = lane & 15;
    const int k4p  = lane >> 4;

    const float* __restrict__ qs = q + ((size_t)bh << 18);

    auto TAf = [](int wid) { return (wid < 4 ? 0 : wid < 7 ? 1 : wid < 9 ? 2 : 3) << 4; };
    auto TCf = [](int wid) { return (wid < 4 ? wid : wid < 7 ? wid - 3 : wid < 9 ? wid - 5 : 3) << 4; };

    float4 sA[8], sB[8], sR[3];

    // ---- issue one unit's 19 coalesced loads (S1 8, S2 8, RL 3) ----
    auto issueUnit = [&](int wid) {
        const int Ta0 = TAf(wid), Tc0 = TCf(wid);
#pragma unroll
        for (int i = 0; i < 8; ++i) {
            const int F = (i << 9) + t;
            const int al = F >> 8, cc = (F >> 4) & 15, g = F & 15;
            sA[i] = *(const float4*)(qs + (size_t)(Ta0 + al) * 4096
                                        + (size_t)(Tc0 + cc) * 64 + (g << 2));
        }
        SBAR;
#pragma unroll
        for (int i = 0; i < 8; ++i) {
            const int F = (i << 9) + t;
            const int al = F >> 8, cc = (F >> 4) & 15, g = F & 15;
            sB[i] = *(const float4*)(qs + (size_t)(Tc0 + al) * 4096
                                        + (size_t)(Ta0 + cc) * 64 + (g << 2));
        }
        SBAR;
#pragma unroll
        for (int m = 0; m < 3; ++m) {
            const int F = (m << 9) + t;
            const int win = F >= 768;
            const int r = F - (win ? 768 : 0);
            const int tbl = r >= 384;
            const int rr = r - (tbl ? 384 : 0);
            const int row = rr >> 4, g = rr & 15;
            const int rb0 = win ? (48 - Ta0) : (48 - Tc0);   // >= 0 always
            int gr = rb0 + row; if (gr > 71) gr = 71;        // junk rows only
            sR[m] = *(const float4*)((tbl ? relw : relh) + (size_t)gr * 64 + (g << 2));
        }
        SBAR;
    };

    // ---- cvt + swizzled LDS writes (wid-independent) ----
    auto writeLDS = [&]() {
#pragma unroll
        for (int i = 0; i < 8; ++i) {
            const int F = (i << 9) + t;
            const int al = F >> 8, cc = (F >> 4) & 15, g = F & 15;
            const int slot = (g >> 1) ^ ((al ^ cc) & 7), half = g & 1;
            uint2 w; w.x = pk(sA[i].x, sA[i].y); w.y = pk(sA[i].z, sA[i].w);
            ((uint2*)&S1[al][cc][slot])[half] = w;
        }
#pragma unroll
        for (int i = 0; i < 8; ++i) {
            const int F = (i << 9) + t;
            const int al = F >> 8, cc = (F >> 4) & 15, g = F & 15;
            const int slot = (g >> 1) ^ ((al ^ cc) & 7), half = g & 1;
            uint2 w; w.x = pk(sB[i].x, sB[i].y); w.y = pk(sB[i].z, sB[i].w);
            ((uint2*)&S2[al][cc][slot])[half] = w;
        }
#pragma unroll
        for (int m = 0; m < 3; ++m) {
            const int F = (m << 9) + t;
            const int win = F >= 768;
            const int r = F - (win ? 768 : 0);
            const int tbl = r >= 384;
            const int rr = r - (tbl ? 384 : 0);
            const int row = rr >> 4, g = rr & 15;
            const int slot = (g >> 1) ^ (row & 7), half = g & 1;
            uint2 w; w.x = pk(sR[m].x, sR[m].y); w.y = pk(sR[m].z, sR[m].w);
            ((uint2*)&RL[win][tbl][row][slot])[half] = w;
        }
    };

    // ---- compute + store one unit (v13 pass, both tile roles by wave group) ----
    auto computeStore = [&](int wid) {
        const int Ta0 = TAf(wid), Tc0 = TCf(wid);
        if (wg == 1 && Ta0 == Tc0) return;   // diag: twin waves idle
        const uint4 (*P)[16][8] = wg ? S2 : S1;
        const uint4 (*Q)[16][8] = wg ? S1 : S2;
        const int win   = wg;
        const int Arow0 = wg ? Tc0 : Ta0;
        const int Ccol0 = wg ? Ta0 : Tc0;

        uint4 A0[4], B0[4], A1[4], B1[4];
        auto RD = [&](int r, uint4* A, uint4* B) {
            const int kh = (r & 1) << 2;
#pragma unroll
            for (int it = 0; it < 4; ++it) {
                const int cl = (wl << 2) | it;
                const int sx = (jl ^ cl) & 7;
                A[it] = (r < 2) ? P[jl][cl][(kh + k4p) ^ sx]
                                : Q[cl][jl][(kh + k4p) ^ sx];
                const int rl = (15 - cl) + jl;           // junk rows if jl>=9
                B[it] = RL[win][r < 2 ? 1 : 0][rl][(kh + k4p) ^ (rl & 7)];
            }
        };
        f32x4 acc[4];
#pragma unroll
        for (int it = 0; it < 4; ++it) acc[it] = (f32x4){0.f, 0.f, 0.f, 0.f};
        auto MF = [&](const uint4* A, const uint4* B) {
#pragma unroll
            for (int it = 0; it < 4; ++it)
                acc[it] = __builtin_amdgcn_mfma_f32_16x16x32_f16(
                    __builtin_bit_cast(f16x8, A[it]),
                    __builtin_bit_cast(f16x8, B[it]), acc[it], 0, 0, 0);
        };
        RD(0, A0, B0); RD(1, A1, B1);
        WAIT_LGKM(8);  MF(A0, B0);  RD(2, A0, B0);
        WAIT_LGKM(8);  MF(A1, B1);  RD(3, A1, B1);
        WAIT_LGKM(8);  MF(A0, B0);
        WAIT_LGKM(0);  MF(A1, B1);

        if (jl < NS) {
            const int ar = k4p << 2;
            const size_t ob = (size_t)bh << 6;
#pragma unroll
            for (int it = 0; it < 4; ++it) {
                const int cl = (wl << 2) | it;
#pragma unroll
                for (int r = 0; r < 4; ++r)
                    out[((ob + (Arow0 + ar + r)) * 64 + (Ccol0 + cl)) * NS + jl] = acc[it][r];
            }
        }
    };

    // ---- persistent loop: prologue + nu units ----
    issueUnit(w0);                        // L_0 in flight
    for (int u = 0; u < nu; ++u) {
        const int wid = w0 + 4 * u;
        if (u > 0) __builtin_amdgcn_s_barrier();   // all reads of unit u-1 done
        WAIT_VM(0);                       // L_u landed (old stores drain too)
        writeLDS();
        if (u + 1 < nu) issueUnit(w0 + 4 * (u + 1));   // stream: L_{u+1} in flight
        WAIT_LGKM(0);
        __builtin_amdgcn_s_barrier();     // publish unit u LDS
        computeStore(wid);
    }
}

extern "C" void kernel_launch(void* const* d_in, const int* in_sizes, int n_in,
                              void* d_out, int out_size, void* d_ws, size_t ws_size,
                              hipStream_t stream) {
    const float* q    = (const float*)d_in[0];
    const float* relh = (const float*)d_in[3];
    const float* relw = (const float*)d_in[4];
    float* out = (float*)d_out;

    // grid: 512 persistent blocks (4 per bh), 512 threads
    relpos_kernel<<<dim3(512), dim3(512), 0, stream>>>(q, relh, relw, out);
}

// Round 16
// 32.980 us; speedup vs baseline: 2.2940x; 1.0414x over previous
//
#include <hip/hip_runtime.h>
#include <stdint.h>

#define NS 9

typedef _Float16 f16x8 __attribute__((ext_vector_type(8)));
typedef float    f32x4 __attribute__((ext_vector_type(4)));

#define SBAR __builtin_amdgcn_sched_barrier(0)
#define WAIT_VM(N) do { SBAR; asm volatile("s_waitcnt vmcnt(" #N ")" ::: "memory"); SBAR; } while (0)
#define WAIT_LGKM(N) do { SBAR; asm volatile("s_waitcnt lgkmcnt(" #N ")" ::: "memory"); SBAR; } while (0)

__device__ __forceinline__ unsigned int pk(float a, float b) {
    return __builtin_bit_cast(unsigned int, __builtin_amdgcn_cvt_pkrtz(a, b));
}

// out[b,h,A,C,j] = sum_d q[b,h,A,C,d]*relw[63+j-C,d] + q[b,h,C,A,d]*relh[63+j-C,d]
// v16 = v13 (31.2us champion: 512-thr pair-tile blocks, 2 blocks/CU) + the
// store path rebuilt: v13 stored 16 masked scalar dwords/lane (36B fragments;
// v14 profile: WRITE_SIZE 70MB vs 18.9 ideal = 3.7x partial-line
// amplification). v16 scatters acc into an f32 LDS out-buffer (reusing S1's
// space after a barrier; row stride 148 floats -> 2-way conflicts only), then
// all 512 threads cooperatively store 576B-contiguous float4 runs, every lane
// active. Everything upstream (staging, swizzles, fragments, MFMA) verbatim
// v13 (passed, absmax 0.03125).

__global__ __launch_bounds__(512, 2) void relpos_kernel(
    const float* __restrict__ q,
    const float* __restrict__ relh,
    const float* __restrict__ relw,
    float* __restrict__ out)
{
    __shared__ uint4 S1[16][16][8];      // 32 KiB f16: q[Ta0+al][Tc0+cc]
    __shared__ uint4 S2[16][16][8];      // 32 KiB f16: q[Tc0+al][Ta0+cc]
    __shared__ uint4 RL[2][2][32][8];    // 16 KiB f16: [win][tbl][row][slot]

    const int blk = blockIdx.x;
    const int bh  = blk & 127;           // b*8+h; stride 128 -> same XCD
    const int wid = blk >> 7;            // 0..9 tile pair
    const int ta  = wid < 4 ? 0 : wid < 7 ? 1 : wid < 9 ? 2 : 3;
    const int tc  = wid < 4 ? wid : wid < 7 ? wid - 3 : wid < 9 ? wid - 5 : 3;
    const int Ta0 = ta << 4, Tc0 = tc << 4;

    const int t    = threadIdx.x;        // 0..511
    const int lane = t & 63;
    const int wvu  = __builtin_amdgcn_readfirstlane(t >> 6);   // 0..7
    const int wg   = wvu >> 2;           // 0: tile (ta,tc), 1: twin (tc,ta)
    const int wl   = wvu & 3;
    const int jl   = lane & 15;
    const int k4p  = lane >> 4;

    const float* __restrict__ qs = q + ((size_t)bh << 18);

    // ---- issue: S1 (8), S2 (8), RL (3) -- all coalesced (verbatim v13) ----
    float4 sA[8], sB[8], sR[3];
#pragma unroll
    for (int i = 0; i < 8; ++i) {
        const int F = (i << 9) + t;
        const int al = F >> 8, cc = (F >> 4) & 15, g = F & 15;
        sA[i] = *(const float4*)(qs + (size_t)(Ta0 + al) * 4096
                                    + (size_t)(Tc0 + cc) * 64 + (g << 2));
    }
    SBAR;
#pragma unroll
    for (int i = 0; i < 8; ++i) {
        const int F = (i << 9) + t;
        const int al = F >> 8, cc = (F >> 4) & 15, g = F & 15;
        sB[i] = *(const float4*)(qs + (size_t)(Tc0 + al) * 4096
                                    + (size_t)(Ta0 + cc) * 64 + (g << 2));
    }
    SBAR;
#pragma unroll
    for (int m = 0; m < 3; ++m) {
        const int F = (m << 9) + t;
        const int win = F >= 768;
        const int r = F - (win ? 768 : 0);
        const int tbl = r >= 384;
        const int rr = r - (tbl ? 384 : 0);
        const int row = rr >> 4, g = rr & 15;
        const int rb0 = win ? (48 - Ta0) : (48 - Tc0);
        int gr = rb0 + row; if (gr > 71) gr = 71;
        sR[m] = *(const float4*)((tbl ? relw : relh) + (size_t)gr * 64 + (g << 2));
    }
    SBAR;

    // ---- drains + cvt + ds_write_b64 (verbatim v13) ----
    WAIT_VM(11);
#pragma unroll
    for (int i = 0; i < 8; ++i) {
        const int F = (i << 9) + t;
        const int al = F >> 8, cc = (F >> 4) & 15, g = F & 15;
        const int slot = (g >> 1) ^ ((al ^ cc) & 7), half = g & 1;
        uint2 w; w.x = pk(sA[i].x, sA[i].y); w.y = pk(sA[i].z, sA[i].w);
        ((uint2*)&S1[al][cc][slot])[half] = w;
    }
    WAIT_VM(3);
#pragma unroll
    for (int i = 0; i < 8; ++i) {
        const int F = (i << 9) + t;
        const int al = F >> 8, cc = (F >> 4) & 15, g = F & 15;
        const int slot = (g >> 1) ^ ((al ^ cc) & 7), half = g & 1;
        uint2 w; w.x = pk(sB[i].x, sB[i].y); w.y = pk(sB[i].z, sB[i].w);
        ((uint2*)&S2[al][cc][slot])[half] = w;
    }
    WAIT_VM(0);
#pragma unroll
    for (int m = 0; m < 3; ++m) {
        const int F = (m << 9) + t;
        const int win = F >= 768;
        const int r = F - (win ? 768 : 0);
        const int tbl = r >= 384;
        const int rr = r - (tbl ? 384 : 0);
        const int row = rr >> 4, g = rr & 15;
        const int slot = (g >> 1) ^ (row & 7), half = g & 1;
        uint2 w; w.x = pk(sR[m].x, sR[m].y); w.y = pk(sR[m].z, sR[m].w);
        ((uint2*)&RL[win][tbl][row][slot])[half] = w;
    }
    WAIT_LGKM(0);
    __builtin_amdgcn_s_barrier();        // (1) publish staged LDS

    // ---- compute (verbatim v13 pipeline), acc hoisted out ----
    const bool active = (wg == 0) || (ta != tc);
    f32x4 acc[4];
#pragma unroll
    for (int it = 0; it < 4; ++it) acc[it] = (f32x4){0.f, 0.f, 0.f, 0.f};

    if (active) {
        const uint4 (*P)[16][8] = wg ? S2 : S1;
        const uint4 (*Q)[16][8] = wg ? S1 : S2;
        const int win = wg;

        uint4 A0[4], B0[4], A1[4], B1[4];
        auto RD = [&](int r, uint4* A, uint4* B) {
            const int kh = (r & 1) << 2;
#pragma unroll
            for (int it = 0; it < 4; ++it) {
                const int cl = (wl << 2) | it;
                const int sx = (jl ^ cl) & 7;
                A[it] = (r < 2) ? P[jl][cl][(kh + k4p) ^ sx]
                                : Q[cl][jl][(kh + k4p) ^ sx];
                const int rl = (15 - cl) + jl;           // junk rows if jl>=9
                B[it] = RL[win][r < 2 ? 1 : 0][rl][(kh + k4p) ^ (rl & 7)];
            }
        };
        auto MF = [&](const uint4* A, const uint4* B) {
#pragma unroll
            for (int it = 0; it < 4; ++it)
                acc[it] = __builtin_amdgcn_mfma_f32_16x16x32_f16(
                    __builtin_bit_cast(f16x8, A[it]),
                    __builtin_bit_cast(f16x8, B[it]), acc[it], 0, 0, 0);
        };
        RD(0, A0, B0); RD(1, A1, B1);
        WAIT_LGKM(8);  MF(A0, B0);  RD(2, A0, B0);
        WAIT_LGKM(8);  MF(A1, B1);  RD(3, A1, B1);
        WAIT_LGKM(8);  MF(A0, B0);
        WAIT_LGKM(0);  MF(A1, B1);
    }

    // ---- store transpose: acc -> LDS (reuse S1 space) -> coalesced float4 ----
    __builtin_amdgcn_s_barrier();        // (2) all frag reads done; S1 reusable
    float* OT = (float*)&S1[0][0][0];    // 2 tiles x 16 rows x 148 floats (18.5KB)
    if (active && jl < NS) {
        const int ar = k4p << 2;
#pragma unroll
        for (int it = 0; it < 4; ++it) {
            const int cbase = (((wl << 2) | it) * NS) + jl;
#pragma unroll
            for (int r = 0; r < 4; ++r)
                OT[wg * 2368 + (ar + r) * 148 + cbase] = acc[it][r];
        }
    }
    WAIT_LGKM(0);
    __builtin_amdgcn_s_barrier();        // (3) OT published

    const int nt = (ta != tc) ? 1152 : 576;   // float4 runs: 2 tiles x 16 x 36
    const size_t ob = (size_t)bh << 6;
    for (int F = t; F < nt; F += 512) {
        const int tile = F >= 576;
        const int rem  = F - (tile ? 576 : 0);
        const int row  = rem / 36;
        const int seg  = rem - row * 36;
        const int Arow0 = tile ? Tc0 : Ta0;
        const int Ccol0 = tile ? Ta0 : Tc0;
        const float4 v = *(const float4*)(OT + tile * 2368 + row * 148 + (seg << 2));
        *(float4*)(out + ((ob + (Arow0 + row)) * 64 + Ccol0) * NS + (seg << 2)) = v;
    }
}

extern "C" void kernel_launch(void* const* d_in, const int* in_sizes, int n_in,
                              void* d_out, int out_size, void* d_ws, size_t ws_size,
                              hipStream_t stream) {
    const float* q    = (const float*)d_in[0];
    const float* relh = (const float*)d_in[3];
    const float* relw = (const float*)d_in[4];
    float* out = (float*)d_out;

    // grid: 10 tile pairs x 128 bh; 512-thread blocks, 80 KiB LDS
    relpos_kernel<<<dim3(1280), dim3(512), 0, stream>>>(q, relh, relw, out);
}

// Round 18
// 29.817 us; speedup vs baseline: 2.5374x; 1.1061x over previous
//
#include <hip/hip_runtime.h>
#include <stdint.h>

#define NS 9

typedef _Float16 f16x8 __attribute__((ext_vector_type(8)));
typedef float    f32x4 __attribute__((ext_vector_type(4)));

#define SBAR __builtin_amdgcn_sched_barrier(0)
#define WAIT_VM(N) do { SBAR; asm volatile("s_waitcnt vmcnt(" #N ")" ::: "memory"); SBAR; } while (0)
#define WAIT_LGKM(N) do { SBAR; asm volatile("s_waitcnt lgkmcnt(" #N ")" ::: "memory"); SBAR; } while (0)

__device__ __forceinline__ unsigned int pk(float a, float b) {
    return __builtin_bit_cast(unsigned int, __builtin_amdgcn_cvt_pkrtz(a, b));
}

// out[b,h,A,C,j] = sum_d q[b,h,A,C,d]*relw[63+j-C,d] + q[b,h,C,A,d]*relh[63+j-C,d]
// v18 = v17 with the off-diag pair enumeration FIXED (v17 bug: wid 3,4 used
// tc=wid-2 -> (1,1),(1,2) instead of (1,2),(1,3); tile (1,3) never written).
// Correct enumeration: (0,1),(0,2),(0,3),(1,2),(1,3),(2,3).
// Structure: per bh, 6 off-diag pair blocks + 2 diag-pack blocks (S1 = tile
// (t0,t0), S2 = tile (t1,t1); diagonal tile needs only its own q-tile in both
// orientations -> Q=P). Grid 1024 = 4 blocks/CU work, 2 resident, all waves
// active, q tile-loads per bh 20 -> 16 (read-once exact). All staging/swizzle/
// fragment/wait formulas verbatim v13 (31.2us champion, absmax 0.03125).

__global__ __launch_bounds__(512, 2) void relpos_kernel(
    const float* __restrict__ q,
    const float* __restrict__ relh,
    const float* __restrict__ relw,
    float* __restrict__ out)
{
    __shared__ uint4 S1[16][16][8];      // 32 KiB f16: q[RA+al][CA+cc]
    __shared__ uint4 S2[16][16][8];      // 32 KiB f16: q[RB+al][CB+cc]
    __shared__ uint4 RL[2][2][32][8];    // 16 KiB f16: [win][tbl][row][slot]

    const int blk = blockIdx.x;
    const int bh  = blk & 127;           // b*8+h; stride 128 -> same XCD
    const int wid = blk >> 7;            // 0..7
    const bool dpack = (wid >= 6);
    int RA, CA, RB, CB;
    if (!dpack) {                        // 6 off-diag pairs (ta<tc)
        const int ta = wid < 3 ? 0 : wid < 5 ? 1 : 2;
        const int tc = wid < 3 ? wid + 1 : wid < 5 ? wid - 1 : 3;
        RA = ta << 4; CA = tc << 4; RB = CA; CB = RA;
    } else {                             // diag-pack: tiles (t0,t0) & (t0+1,t0+1)
        const int t0 = (wid - 6) << 1;
        RA = CA = t0 << 4; RB = CB = (t0 + 1) << 4;
    }

    const int t    = threadIdx.x;        // 0..511
    const int lane = t & 63;
    const int wvu  = __builtin_amdgcn_readfirstlane(t >> 6);   // 0..7
    const int wg   = wvu >> 2;           // 0: tile (RA,CA), 1: tile (RB,CB)
    const int wl   = wvu & 3;
    const int jl   = lane & 15;
    const int k4p  = lane >> 4;

    const float* __restrict__ qs = q + ((size_t)bh << 18);

    // ---- issue: S1 (8), S2 (8), RL (3) -- all coalesced (verbatim v13) ----
    float4 sA[8], sB[8], sR[3];
#pragma unroll
    for (int i = 0; i < 8; ++i) {
        const int F = (i << 9) + t;
        const int al = F >> 8, cc = (F >> 4) & 15, g = F & 15;
        sA[i] = *(const float4*)(qs + (size_t)(RA + al) * 4096
                                    + (size_t)(CA + cc) * 64 + (g << 2));
    }
    SBAR;
#pragma unroll
    for (int i = 0; i < 8; ++i) {
        const int F = (i << 9) + t;
        const int al = F >> 8, cc = (F >> 4) & 15, g = F & 15;
        sB[i] = *(const float4*)(qs + (size_t)(RB + al) * 4096
                                    + (size_t)(CB + cc) * 64 + (g << 2));
    }
    SBAR;
#pragma unroll
    for (int m = 0; m < 3; ++m) {
        const int F = (m << 9) + t;
        const int win = F >= 768;
        const int r = F - (win ? 768 : 0);
        const int tbl = r >= 384;
        const int rr = r - (tbl ? 384 : 0);
        const int row = rr >> 4, g = rr & 15;
        const int rb0 = win ? (48 - CB) : (48 - CA);
        int gr = rb0 + row; if (gr > 71) gr = 71;        // junk rows only
        sR[m] = *(const float4*)((tbl ? relw : relh) + (size_t)gr * 64 + (g << 2));
    }
    SBAR;

    // ---- drains + cvt + ds_write_b64 (verbatim v13) ----
    WAIT_VM(11);
#pragma unroll
    for (int i = 0; i < 8; ++i) {
        const int F = (i << 9) + t;
        const int al = F >> 8, cc = (F >> 4) & 15, g = F & 15;
        const int slot = (g >> 1) ^ ((al ^ cc) & 7), half = g & 1;
        uint2 w; w.x = pk(sA[i].x, sA[i].y); w.y = pk(sA[i].z, sA[i].w);
        ((uint2*)&S1[al][cc][slot])[half] = w;
    }
    WAIT_VM(3);
#pragma unroll
    for (int i = 0; i < 8; ++i) {
        const int F = (i << 9) + t;
        const int al = F >> 8, cc = (F >> 4) & 15, g = F & 15;
        const int slot = (g >> 1) ^ ((al ^ cc) & 7), half = g & 1;
        uint2 w; w.x = pk(sB[i].x, sB[i].y); w.y = pk(sB[i].z, sB[i].w);
        ((uint2*)&S2[al][cc][slot])[half] = w;
    }
    WAIT_VM(0);
#pragma unroll
    for (int m = 0; m < 3; ++m) {
        const int F = (m << 9) + t;
        const int win = F >= 768;
        const int r = F - (win ? 768 : 0);
        const int tbl = r >= 384;
        const int rr = r - (tbl ? 384 : 0);
        const int row = rr >> 4, g = rr & 15;
        const int slot = (g >> 1) ^ (row & 7), half = g & 1;
        uint2 w; w.x = pk(sR[m].x, sR[m].y); w.y = pk(sR[m].z, sR[m].w);
        ((uint2*)&RL[win][tbl][row][slot])[half] = w;
    }
    WAIT_LGKM(0);
    __builtin_amdgcn_s_barrier();        // publish LDS

    // ---- compute: every wave active ----
    {
        const uint4 (*P)[16][8] = wg ? S2 : S1;
        const uint4 (*Q)[16][8] = dpack ? P : (wg ? S1 : S2);
        const int win   = wg;
        const int Arow0 = wg ? RB : RA;
        const int Ccol0 = wg ? CB : CA;

        uint4 A0[4], B0[4], A1[4], B1[4];
        auto RD = [&](int r, uint4* A, uint4* B) {
            const int kh = (r & 1) << 2;
#pragma unroll
            for (int it = 0; it < 4; ++it) {
                const int cl = (wl << 2) | it;
                const int sx = (jl ^ cl) & 7;
                A[it] = (r < 2) ? P[jl][cl][(kh + k4p) ^ sx]
                                : Q[cl][jl][(kh + k4p) ^ sx];
                const int rl = (15 - cl) + jl;           // junk rows if jl>=9
                B[it] = RL[win][r < 2 ? 1 : 0][rl][(kh + k4p) ^ (rl & 7)];
            }
        };
        f32x4 acc[4];
#pragma unroll
        for (int it = 0; it < 4; ++it) acc[it] = (f32x4){0.f, 0.f, 0.f, 0.f};
        auto MF = [&](const uint4* A, const uint4* B) {
#pragma unroll
            for (int it = 0; it < 4; ++it)
                acc[it] = __builtin_amdgcn_mfma_f32_16x16x32_f16(
                    __builtin_bit_cast(f16x8, A[it]),
                    __builtin_bit_cast(f16x8, B[it]), acc[it], 0, 0, 0);
        };
        RD(0, A0, B0); RD(1, A1, B1);
        WAIT_LGKM(8);  MF(A0, B0);  RD(2, A0, B0);
        WAIT_LGKM(8);  MF(A1, B1);  RD(3, A1, B1);
        WAIT_LGKM(8);  MF(A0, B0);
        WAIT_LGKM(0);  MF(A1, B1);

        // ---- store (verbatim v13): col j=lane&15 (<9), row=(lane>>4)*4+reg ----
        if (jl < NS) {
            const int ar = k4p << 2;
            const size_t ob = (size_t)bh << 6;
#pragma unroll
            for (int it = 0; it < 4; ++it) {
                const int cl = (wl << 2) | it;
#pragma unroll
                for (int r = 0; r < 4; ++r)
                    out[((ob + (Arow0 + ar + r)) * 64 + (Ccol0 + cl)) * NS + jl] = acc[it][r];
            }
        }
    }
}

extern "C" void kernel_launch(void* const* d_in, const int* in_sizes, int n_in,
                              void* d_out, int out_size, void* d_ws, size_t ws_size,
                              hipStream_t stream) {
    const float* q    = (const float*)d_in[0];
    const float* relh = (const float*)d_in[3];
    const float* relw = (const float*)d_in[4];
    float* out = (float*)d_out;

    // grid: 8 blocks per bh (6 off-diag pairs + 2 diag-packs) x 128 bh
    relpos_kernel<<<dim3(1024), dim3(512), 0, stream>>>(q, relh, relw, out);
}